// Round 5
// baseline (291.765 us; speedup 1.0000x reference)
//
#include <hip/hip_runtime.h>

typedef unsigned short u16;
typedef __bf16 bf16x8 __attribute__((ext_vector_type(8)));
typedef float f32x4 __attribute__((ext_vector_type(4)));

__device__ __forceinline__ float bf2f(u16 u) {
  return __builtin_bit_cast(float, (unsigned)u << 16);
}
__device__ __forceinline__ u16 f2bf(float f) {
  unsigned u = __builtin_bit_cast(unsigned, f);
  u += 0x7FFFu + ((u >> 16) & 1u);  // RNE
  return (u16)(u >> 16);
}
__device__ __forceinline__ unsigned pk2(float a, float b) {
  return (unsigned)f2bf(a) | ((unsigned)f2bf(b) << 16);
}
__device__ __forceinline__ f32x4 mfma16(bf16x8 a, bf16x8 b, f32x4 c) {
  return __builtin_amdgcn_mfma_f32_16x16x32_bf16(a, b, c, 0, 0, 0);
}
// async 16B/lane global->LDS; LDS dest = wave-uniform base + lane*16
__device__ __forceinline__ void async_cp16(const u16* g, u16* l) {
  __builtin_amdgcn_global_load_lds((const __attribute__((address_space(1))) void*)g,
                                   (__attribute__((address_space(3))) void*)l, 16, 0, 0);
}
#define S_BARRIER() asm volatile("s_barrier" ::: "memory")

// ---------------------------------------------------------------------------
__global__ __launch_bounds__(256) void cast_f32_bf16(const float* __restrict__ in,
                                                     u16* __restrict__ out, int n) {
  int idx = (blockIdx.x * 256 + threadIdx.x) * 4;
  if (idx < n) {
    float4 f = *(const float4*)&in[idx];
    ushort4 o;
    o.x = f2bf(f.x); o.y = f2bf(f.y); o.z = f2bf(f.z); o.w = f2bf(f.w);
    *(ushort4*)&out[idx] = o;
  }
}

__global__ __launch_bounds__(256) void biascat(const float* __restrict__ bq,
                                               const float* __restrict__ bk,
                                               const float* __restrict__ bv,
                                               float* __restrict__ o) {
  int i = blockIdx.x * 256 + threadIdx.x;
  if (i < 3072)
    o[i] = i < 1024 ? bq[i] : (i < 2048 ? bk[i - 1024] : bv[i - 2048]);
}

// ---------------------------------------------------------------------------
// 7 weight transposes fused: [R][1024] f32 -> [1024][R] bf16. grid (16,16,7).
// ---------------------------------------------------------------------------
#define TSP 72
__global__ __launch_bounds__(256) void transpose_weights(
    const float* __restrict__ We, const float* __restrict__ Wq,
    const float* __restrict__ Wk, const float* __restrict__ Wv,
    const float* __restrict__ W0, const float* __restrict__ W1,
    const float* __restrict__ W2, u16* Wet, u16* qkvWt, u16* W0t, u16* W1t,
    u16* W2t) {
  const int z = blockIdx.z;
  const float* in;
  u16* out;
  int out_rs = 1024;
  if (z == 0) { if (blockIdx.y >= 8) return; in = We; out = Wet; out_rs = 512; }
  else if (z == 1) { in = Wq; out = qkvWt; }
  else if (z == 2) { in = Wk; out = qkvWt + 1048576; }
  else if (z == 3) { in = Wv; out = qkvWt + 2097152; }
  else if (z == 4) { in = W0; out = W0t; }
  else if (z == 5) { in = W1; out = W1t; }
  else { in = W2; out = W2t; }
  __shared__ alignas(16) u16 T[64][TSP];
  const int tid = threadIdx.x;
  const int r0 = blockIdx.y * 64, c0 = blockIdx.x * 64;
#pragma unroll
  for (int it = 0; it < 4; ++it) {
    int vi = it * 256 + tid;
    int i = vi >> 4, j4 = (vi & 15) * 4;
    float4 f = *(const float4*)&in[(size_t)(r0 + i) * 1024 + c0 + j4];
    T[i][j4 + 0] = f2bf(f.x);
    T[i][j4 + 1] = f2bf(f.y);
    T[i][j4 + 2] = f2bf(f.z);
    T[i][j4 + 3] = f2bf(f.w);
  }
  __syncthreads();
#pragma unroll
  for (int it = 0; it < 2; ++it) {
    int vi = it * 256 + tid;
    int i = vi >> 3, j8 = (vi & 7) * 8;
    bf16x8 v;
#pragma unroll
    for (int u = 0; u < 8; ++u) ((u16*)&v)[u] = T[j8 + u][i];
    *(bf16x8*)&out[(size_t)(c0 + i) * out_rs + r0 + j8] = v;
  }
}

// ---------------------------------------------------------------------------
// GEMM: C[M,N] = act(A @ Bt^T + bias [+res]). TN=64, BK=64, 4 waves.
// TM=128: wave 64x32 (4x2), LDS 48KB, 3 blk/CU. TM=64: wave 32x32 (2x2),
// LDS 32KB, 5 blk/CU. Async dbuf global_load_lds, raw barriers, XOR swizzle.
// ---------------------------------------------------------------------------
template <int TM>
__global__ __launch_bounds__(256, (TM == 128) ? 3 : 5) void gemm_mfma(
    const u16* __restrict__ A, const u16* __restrict__ Bt,
    const float* __restrict__ bias, const u16* __restrict__ res,
    void* __restrict__ Cout, int M, int N, int K, int relu, int f32out) {
  constexpr int MT = TM / 32;       // m-tiles per wave
  constexpr int AI = TM / 32;       // A staging issues per lane
  __shared__ alignas(16) u16 As[2][TM * 64];
  __shared__ alignas(16) u16 Bs[2][64 * 64];
  const int tid = threadIdx.x;
  const int wave = tid >> 6, lane = tid & 63;
  const int quad = lane >> 4, l16 = lane & 15;
  const int m0 = blockIdx.y * TM, n0 = blockIdx.x * 64;
  const int wm = (wave & 1) * (TM / 2), wn = (wave >> 1) * 32;

  f32x4 acc[MT][2];
#pragma unroll
  for (int i = 0; i < MT; ++i)
#pragma unroll
    for (int j = 0; j < 2; ++j) acc[i][j] = (f32x4){0.f, 0.f, 0.f, 0.f};

  const int srow = lane >> 3;                   // 0..7
  const int schunk = (lane & 7) ^ (srow & 7);   // XOR swizzle on global side
  const u16* Ag = A + (size_t)(m0 + wave * (TM / 4) + srow) * K + schunk * 8;
  const u16* Bg = Bt + (size_t)(n0 + wave * 16 + srow) * K + schunk * 8;
  u16* AsW0 = &As[0][wave * (TM / 4) * 64];
  u16* BsW0 = &Bs[0][wave * 16 * 64];
  u16* AsW1 = &As[1][wave * (TM / 4) * 64];
  u16* BsW1 = &Bs[1][wave * 16 * 64];

#define GEMM_ISSUE(ab, bb, k)                                     \
  {                                                               \
    _Pragma("unroll") for (int i = 0; i < AI; ++i)                \
        async_cp16(Ag + (k) + (size_t)i * 8 * K, (ab) + i * 512); \
    _Pragma("unroll") for (int i = 0; i < 2; ++i)                 \
        async_cp16(Bg + (k) + (size_t)i * 8 * K, (bb) + i * 512); \
  }

  GEMM_ISSUE(AsW0, BsW0, 0);
  const int T = K >> 6;
  const int swz = (l16 & 7);
  for (int t = 0; t < T; ++t) {
    const int cb = t & 1;
    S_BARRIER();  // prior compute on buf cb^1 finished everywhere
    const int kn = (t + 1 < T) ? ((t + 1) << 6) : 0;  // wrap: harmless refetch
    if (cb == 0) GEMM_ISSUE(AsW1, BsW1, kn) else GEMM_ISSUE(AsW0, BsW0, kn);
    if constexpr (TM == 128)
      asm volatile("s_waitcnt vmcnt(6)" ::: "memory");  // tile-t loads landed
    else
      asm volatile("s_waitcnt vmcnt(4)" ::: "memory");
    S_BARRIER();
#pragma unroll
    for (int kk = 0; kk < 2; ++kk) {
      bf16x8 af[MT], bfr[2];
#pragma unroll
      for (int mt = 0; mt < MT; ++mt)
        af[mt] = *(const bf16x8*)&As[cb][(wm + mt * 16 + l16) * 64 +
                                        ((kk * 4 + quad) ^ swz) * 8];
#pragma unroll
      for (int nt = 0; nt < 2; ++nt)
        bfr[nt] = *(const bf16x8*)&Bs[cb][(wn + nt * 16 + l16) * 64 +
                                          ((kk * 4 + quad) ^ swz) * 8];
#pragma unroll
      for (int mt = 0; mt < MT; ++mt)
#pragma unroll
        for (int nt = 0; nt < 2; ++nt)
          acc[mt][nt] = mfma16(af[mt], bfr[nt], acc[mt][nt]);
    }
  }
  asm volatile("s_waitcnt vmcnt(0)" ::: "memory");  // drain before LDS dealloc

#pragma unroll
  for (int nt = 0; nt < 2; ++nt) {
    int col = n0 + wn + nt * 16 + l16;
    float bv = bias[col];
#pragma unroll
    for (int mt = 0; mt < MT; ++mt) {
#pragma unroll
      for (int r = 0; r < 4; ++r) {
        int row = m0 + wm + mt * 16 + quad * 4 + r;  // D: row=quad*4+r, col=l16
        float v = acc[mt][nt][r] + bv;
        if (res) v += bf2f(res[(size_t)row * N + col]);
        if (relu) v = fmaxf(v, 0.f);
        if (f32out)
          ((float*)Cout)[(size_t)row * N + col] = v;
        else
          ((u16*)Cout)[(size_t)row * N + col] = f2bf(v);
      }
    }
  }
}

// ---------------------------------------------------------------------------
// Flash attention, transposed form: S^T = K@Q^T, ctx^T = V^T@P^T.
// Fixed-base softmax (Q pre-scaled 1/8). qkv [B,S,3072]; Vt [B,H,64,S].
// Block = 64 q-rows x (h,b); wave = 16 q-rows. 64-key tiles, dbuf staging.
// grid (32,16,2) = 1024 blocks; LDS 41KB -> 3 blk/CU.
// ---------------------------------------------------------------------------
__global__ __launch_bounds__(256, 3) void attn_kernel(
    const u16* __restrict__ QKV, const u16* __restrict__ Vt,
    u16* __restrict__ O) {
  __shared__ alignas(16) u16 Ks[2][64 * 64];  // [key][d], swizzled
  __shared__ alignas(16) u16 Vs[2][64 * 64];  // [d][s], swizzled
  __shared__ alignas(16) u16 Ps[4][16 * 72];  // per-wave P[qrow][key]
  const int tid = threadIdx.x;
  const int wave = tid >> 6, lane = tid & 63;
  const int quad = lane >> 4, l16 = lane & 15;
  const int b = blockIdx.z, h = blockIdx.y;
  const int q0 = blockIdx.x * 64 + wave * 16;

  // Q as B-frags (k=d=quad*8+j, n=qrow=l16), pre-scaled by 1/8 (exact)
  bf16x8 qf[2];
  {
    const size_t qoff = (size_t)(b * 2048 + q0 + l16) * 3072 + h * 64;
#pragma unroll
    for (int kk = 0; kk < 2; ++kk) {
      bf16x8 raw = *(const bf16x8*)&QKV[qoff + kk * 32 + quad * 8];
#pragma unroll
      for (int u = 0; u < 8; ++u)
        ((u16*)&raw)[u] = f2bf(0.125f * bf2f(((u16*)&raw)[u]));
      qf[kk] = raw;
    }
  }

  f32x4 o[4];  // ctx^T [d-tile]
#pragma unroll
  for (int mt = 0; mt < 4; ++mt) o[mt] = (f32x4){0.f, 0.f, 0.f, 0.f};
  float lsum = 0.f;

  const int srow = lane >> 3;
  const int schunk = (lane & 7) ^ (srow & 7);
  const u16* Kg = QKV + (size_t)(b * 2048 + wave * 16 + srow) * 3072 + 1024 +
                  h * 64 + schunk * 8;
  const u16* Vg = Vt + (size_t)((b * 16 + h) * 64 + wave * 16 + srow) * 2048 +
                  schunk * 8;
  u16* KsW0 = &Ks[0][(wave * 16) * 64];
  u16* VsW0 = &Vs[0][(wave * 16) * 64];
  u16* KsW1 = &Ks[1][(wave * 16) * 64];
  u16* VsW1 = &Vs[1][(wave * 16) * 64];

#define ATTN_ISSUE(kb, vb, kt)                                \
  {                                                           \
    async_cp16(Kg + (size_t)(kt) * 3072, (kb));               \
    async_cp16(Kg + (size_t)((kt) + 8) * 3072, (kb) + 512);   \
    async_cp16(Vg + (kt), (vb));                              \
    async_cp16(Vg + (kt) + (size_t)8 * 2048, (vb) + 512);     \
  }

  ATTN_ISSUE(KsW0, VsW0, 0);
  const int swz = (l16 & 7);
  u16* PsW = &Ps[wave][0];
  for (int t = 0; t < 32; ++t) {
    const int cb = t & 1;
    S_BARRIER();
    const int ktn = (t + 1 < 32) ? ((t + 1) * 64) : 0;
    if (cb == 0) ATTN_ISSUE(KsW1, VsW1, ktn) else ATTN_ISSUE(KsW0, VsW0, ktn);
    asm volatile("s_waitcnt vmcnt(4)" ::: "memory");
    S_BARRIER();

    // S^T = K @ Q^T : D[m=key][n=qrow]
    f32x4 st[4];
#pragma unroll
    for (int km = 0; km < 4; ++km) st[km] = (f32x4){0.f, 0.f, 0.f, 0.f};
#pragma unroll
    for (int kk = 0; kk < 2; ++kk)
#pragma unroll
      for (int km = 0; km < 4; ++km) {
        bf16x8 kf = *(const bf16x8*)&Ks[cb][(km * 16 + l16) * 64 +
                                           ((kk * 4 + quad) ^ swz) * 8];
        st[km] = mfma16(kf, qf[kk], st[km]);
      }

    // exp + pack 4 keys -> one b64 LDS write; P[qrow][key] key-contiguous
#pragma unroll
    for (int km = 0; km < 4; ++km) {
      float e0 = __expf(st[km][0]), e1 = __expf(st[km][1]);
      float e2 = __expf(st[km][2]), e3 = __expf(st[km][3]);
      lsum += (e0 + e1) + (e2 + e3);
      uint2 pk;
      pk.x = pk2(e0, e1);
      pk.y = pk2(e2, e3);
      *(uint2*)&PsW[l16 * 72 + km * 16 + quad * 4] = pk;
    }
    asm volatile("s_waitcnt lgkmcnt(0)" ::: "memory");  // wave-local round-trip

    // ctx^T += V^T @ P^T
#pragma unroll
    for (int kk2 = 0; kk2 < 2; ++kk2) {
      bf16x8 pf = *(const bf16x8*)&PsW[l16 * 72 + kk2 * 32 + quad * 8];
#pragma unroll
      for (int mt = 0; mt < 4; ++mt) {
        bf16x8 vf = *(const bf16x8*)&Vs[cb][(mt * 16 + l16) * 64 +
                                           ((kk2 * 4 + quad) ^ swz) * 8];
        o[mt] = mfma16(vf, pf, o[mt]);
      }
    }
  }
  asm volatile("s_waitcnt vmcnt(0)" ::: "memory");  // drain before LDS dealloc

  // epilogue: lane holds ctx^T[d=mt*16+quad*4+r][qrow=l16] -> packed 8B
  {
    float l = lsum;
    l += __shfl_xor(l, 16);
    l += __shfl_xor(l, 32);
    float inv = 1.f / l;
    size_t base = (size_t)(b * 2048 + q0 + l16) * 1024 + h * 64;
#pragma unroll
    for (int mt = 0; mt < 4; ++mt) {
      uint2 pk;
      pk.x = pk2(o[mt][0] * inv, o[mt][1] * inv);
      pk.y = pk2(o[mt][2] * inv, o[mt][3] * inv);
      *(uint2*)&O[base + mt * 16 + quad * 4] = pk;
    }
  }
}

// v slice of qkv [B,S,3072] -> vt [B,H,64,S]; grid (S/64, B*H)
__global__ __launch_bounds__(256) void transpose_v(const u16* __restrict__ QKV,
                                                   u16* __restrict__ vt) {
  const int bh = blockIdx.y;
  const int b = bh >> 4, h = bh & 15;
  const int s0 = blockIdx.x * 64;
  const u16* in = QKV + (size_t)b * 2048 * 3072 + 2048 + h * 64;
  u16* out = vt + (size_t)bh * 131072;
  __shared__ alignas(16) u16 T[64][TSP];
  const int tid = threadIdx.x;
#pragma unroll
  for (int it = 0; it < 2; ++it) {
    int vi = it * 256 + tid;
    int i = vi >> 3, j8 = (vi & 7) * 8;
    *(bf16x8*)&T[i][j8] = *(const bf16x8*)&in[(size_t)(s0 + i) * 3072 + j8];
  }
  __syncthreads();
#pragma unroll
  for (int it = 0; it < 2; ++it) {
    int vi = it * 256 + tid;
    int i = vi >> 3, j8 = (vi & 7) * 8;  // i = d, j8 over s
    bf16x8 vv;
#pragma unroll
    for (int u = 0; u < 8; ++u) ((u16*)&vv)[u] = T[j8 + u][i];
    *(bf16x8*)&out[(size_t)i * 2048 + s0 + j8] = vv;
  }
}

// ---------------------------------------------------------------------------
extern "C" void kernel_launch(void* const* d_in, const int* in_sizes, int n_in,
                              void* d_out, int out_size, void* d_ws,
                              size_t ws_size, hipStream_t stream) {
  const float* x = (const float*)d_in[0];
  const float* We = (const float*)d_in[1];
  const float* be = (const float*)d_in[2];
  const float* Wq = (const float*)d_in[3];
  const float* bq = (const float*)d_in[4];
  const float* Wk = (const float*)d_in[5];
  const float* bk = (const float*)d_in[6];
  const float* Wv = (const float*)d_in[7];
  const float* bv = (const float*)d_in[8];
  const float* W0 = (const float*)d_in[9];
  const float* b0 = (const float*)d_in[10];
  const float* W1 = (const float*)d_in[11];
  const float* b1 = (const float*)d_in[12];
  const float* W2 = (const float*)d_in[13];
  const float* b2 = (const float*)d_in[14];

  u16* ws = (u16*)d_ws;
  u16* xb = ws;                         // 2,097,152
  u16* Wet = xb + 2097152;              //   524,288
  u16* qkvWt = Wet + 524288;            // 3,145,728
  u16* ctx = ws;                        // alias after qkv-gemm
  u16* W0t = qkvWt + 3145728;
  u16* W1t = W0t + 1048576;
  u16* W2t = W1t + 1048576;
  float* biasqkv = (float*)(W2t + 1048576);  // 3072 f32
  u16* e = W2t + 1048576 + 6144;
  u16* qkv = e + 4194304;               // 12,582,912
  u16* vtb = qkv + 12582912;
  u16* mha = qkv;                       // alias: qkv dead after attn
  u16* h1 = e;                          // alias: e dead after W0-gemm

  cast_f32_bf16<<<2048, 256, 0, stream>>>(x, xb, 4096 * 512);
  transpose_weights<<<dim3(16, 16, 7), 256, 0, stream>>>(
      We, Wq, Wk, Wv, W0, W1, W2, Wet, qkvWt, W0t, W1t, W2t);
  biascat<<<12, 256, 0, stream>>>(bq, bk, bv, biasqkv);

  // e = x @ We + be
  gemm_mfma<64><<<dim3(16, 64), 256, 0, stream>>>(xb, Wet, be, nullptr, e,
                                                  4096, 1024, 512, 0, 0);
  // qkv = e @ [Wq|Wk|Wv] + [bq|bk|bv]
  gemm_mfma<128><<<dim3(48, 32), 256, 0, stream>>>(e, qkvWt, biasqkv, nullptr,
                                                   qkv, 4096, 3072, 1024, 0, 0);
  transpose_v<<<dim3(32, 32), 256, 0, stream>>>(qkv, vtb);
  attn_kernel<<<dim3(32, 16, 2), 256, 0, stream>>>(qkv, vtb, ctx);
  // mha = e + ctx @ W0 + b0
  gemm_mfma<64><<<dim3(16, 64), 256, 0, stream>>>(ctx, W0t, b0, e, mha, 4096,
                                                  1024, 1024, 0, 0);
  // h1 = relu(mha @ W1 + b1)
  gemm_mfma<64><<<dim3(16, 64), 256, 0, stream>>>(mha, W1t, b1, nullptr, h1,
                                                  4096, 1024, 1024, 1, 0);
  // out = mha + h1 @ W2 + b2 (f32)
  gemm_mfma<64><<<dim3(16, 64), 256, 0, stream>>>(h1, W2t, b2, mha, d_out,
                                                  4096, 1024, 1024, 0, 1);
}

// Round 6
// 259.116 us; speedup vs baseline: 1.1260x; 1.1260x over previous
//
#include <hip/hip_runtime.h>

typedef unsigned short u16;
typedef __bf16 bf16x8 __attribute__((ext_vector_type(8)));
typedef float f32x4 __attribute__((ext_vector_type(4)));

__device__ __forceinline__ float bf2f(u16 u) {
  return __builtin_bit_cast(float, (unsigned)u << 16);
}
__device__ __forceinline__ u16 f2bf(float f) {
  unsigned u = __builtin_bit_cast(unsigned, f);
  u += 0x7FFFu + ((u >> 16) & 1u);  // RNE
  return (u16)(u >> 16);
}
__device__ __forceinline__ unsigned pk2(float a, float b) {
  return (unsigned)f2bf(a) | ((unsigned)f2bf(b) << 16);
}
// truncating pack: [b.hi16 | a.hi16] in ONE v_perm_b32 (bias cancels in P/l)
__device__ __forceinline__ unsigned pk2t(float a, float b) {
  return __builtin_amdgcn_perm(__builtin_bit_cast(unsigned, b),
                               __builtin_bit_cast(unsigned, a), 0x07060302u);
}
__device__ __forceinline__ f32x4 mfma16(bf16x8 a, bf16x8 b, f32x4 c) {
  return __builtin_amdgcn_mfma_f32_16x16x32_bf16(a, b, c, 0, 0, 0);
}
// async 16B/lane global->LDS; LDS dest = wave-uniform base + lane*16
__device__ __forceinline__ void async_cp16(const u16* g, u16* l) {
  __builtin_amdgcn_global_load_lds((const __attribute__((address_space(1))) void*)g,
                                   (__attribute__((address_space(3))) void*)l, 16, 0, 0);
}
#define S_BARRIER() asm volatile("s_barrier" ::: "memory")

// ---------------------------------------------------------------------------
__global__ __launch_bounds__(256) void cast_f32_bf16(const float* __restrict__ in,
                                                     u16* __restrict__ out, int n) {
  int idx = (blockIdx.x * 256 + threadIdx.x) * 4;
  if (idx < n) {
    float4 f = *(const float4*)&in[idx];
    ushort4 o;
    o.x = f2bf(f.x); o.y = f2bf(f.y); o.z = f2bf(f.z); o.w = f2bf(f.w);
    *(ushort4*)&out[idx] = o;
  }
}

__global__ __launch_bounds__(256) void biascat(const float* __restrict__ bq,
                                               const float* __restrict__ bk,
                                               const float* __restrict__ bv,
                                               float* __restrict__ o) {
  int i = blockIdx.x * 256 + threadIdx.x;
  if (i < 3072)
    o[i] = i < 1024 ? bq[i] : (i < 2048 ? bk[i - 1024] : bv[i - 2048]);
}

// ---------------------------------------------------------------------------
// 7 weight transposes fused: [R][1024] f32 -> [1024][R] bf16. grid (16,16,7).
// ---------------------------------------------------------------------------
#define TSP 72
__global__ __launch_bounds__(256) void transpose_weights(
    const float* __restrict__ We, const float* __restrict__ Wq,
    const float* __restrict__ Wk, const float* __restrict__ Wv,
    const float* __restrict__ W0, const float* __restrict__ W1,
    const float* __restrict__ W2, u16* Wet, u16* qkvWt, u16* W0t, u16* W1t,
    u16* W2t) {
  const int z = blockIdx.z;
  const float* in;
  u16* out;
  int out_rs = 1024;
  if (z == 0) { if (blockIdx.y >= 8) return; in = We; out = Wet; out_rs = 512; }
  else if (z == 1) { in = Wq; out = qkvWt; }
  else if (z == 2) { in = Wk; out = qkvWt + 1048576; }
  else if (z == 3) { in = Wv; out = qkvWt + 2097152; }
  else if (z == 4) { in = W0; out = W0t; }
  else if (z == 5) { in = W1; out = W1t; }
  else { in = W2; out = W2t; }
  __shared__ alignas(16) u16 T[64][TSP];
  const int tid = threadIdx.x;
  const int r0 = blockIdx.y * 64, c0 = blockIdx.x * 64;
#pragma unroll
  for (int it = 0; it < 4; ++it) {
    int vi = it * 256 + tid;
    int i = vi >> 4, j4 = (vi & 15) * 4;
    float4 f = *(const float4*)&in[(size_t)(r0 + i) * 1024 + c0 + j4];
    T[i][j4 + 0] = f2bf(f.x);
    T[i][j4 + 1] = f2bf(f.y);
    T[i][j4 + 2] = f2bf(f.z);
    T[i][j4 + 3] = f2bf(f.w);
  }
  __syncthreads();
#pragma unroll
  for (int it = 0; it < 2; ++it) {
    int vi = it * 256 + tid;
    int i = vi >> 3, j8 = (vi & 7) * 8;
    bf16x8 v;
#pragma unroll
    for (int u = 0; u < 8; ++u) ((u16*)&v)[u] = T[j8 + u][i];
    *(bf16x8*)&out[(size_t)(c0 + i) * out_rs + r0 + j8] = v;
  }
}

// ---------------------------------------------------------------------------
// GEMM: C[M,N] = act(A @ Bt^T + bias [+res]). TN=64, BK=64, 4 waves, M=4096.
// 1D grid, XCD-swizzled: blocks i=k (mod 8) share XCD k and a 512-row
// A-window (1MB, L2-resident) across all N-strips.
// TM=128: wave 64x32; TM=64: wave 32x32. Async dbuf, raw barriers, XOR swz.
// ---------------------------------------------------------------------------
template <int TM>
__global__ __launch_bounds__(256, (TM == 128) ? 3 : 5) void gemm_mfma(
    const u16* __restrict__ A, const u16* __restrict__ Bt,
    const float* __restrict__ bias, const u16* __restrict__ res,
    void* __restrict__ Cout, int M, int N, int K, int relu, int f32out) {
  constexpr int MT = TM / 32;       // m-tiles per wave
  constexpr int AI = TM / 32;       // A staging issues per lane
  __shared__ alignas(16) u16 As[2][TM * 64];
  __shared__ alignas(16) u16 Bs[2][64 * 64];
  const int tid = threadIdx.x;
  const int wave = tid >> 6, lane = tid & 63;
  const int quad = lane >> 4, l16 = lane & 15;
  // XCD swizzle decode (M=4096 fixed): 8 XCD groups x YB y-blocks x NX strips
  const int ib = blockIdx.x;
  int by, bx;
  if constexpr (TM == 128) { by = (ib & 7) * 4 + ((ib >> 3) & 3); bx = ib >> 5; }
  else { by = (ib & 7) * 8 + ((ib >> 3) & 7); bx = ib >> 6; }
  const int m0 = by * TM, n0 = bx * 64;
  const int wm = (wave & 1) * (TM / 2), wn = (wave >> 1) * 32;

  f32x4 acc[MT][2];
#pragma unroll
  for (int i = 0; i < MT; ++i)
#pragma unroll
    for (int j = 0; j < 2; ++j) acc[i][j] = (f32x4){0.f, 0.f, 0.f, 0.f};

  const int srow = lane >> 3;                   // 0..7
  const int schunk = (lane & 7) ^ (srow & 7);   // XOR swizzle on global side
  const u16* Ag = A + (size_t)(m0 + wave * (TM / 4) + srow) * K + schunk * 8;
  const u16* Bg = Bt + (size_t)(n0 + wave * 16 + srow) * K + schunk * 8;
  u16* AsW0 = &As[0][wave * (TM / 4) * 64];
  u16* BsW0 = &Bs[0][wave * 16 * 64];
  u16* AsW1 = &As[1][wave * (TM / 4) * 64];
  u16* BsW1 = &Bs[1][wave * 16 * 64];

#define GEMM_ISSUE(ab, bb, k)                                     \
  {                                                               \
    _Pragma("unroll") for (int i = 0; i < AI; ++i)                \
        async_cp16(Ag + (k) + (size_t)i * 8 * K, (ab) + i * 512); \
    _Pragma("unroll") for (int i = 0; i < 2; ++i)                 \
        async_cp16(Bg + (k) + (size_t)i * 8 * K, (bb) + i * 512); \
  }

  GEMM_ISSUE(AsW0, BsW0, 0);
  const int T = K >> 6;
  const int swz = (l16 & 7);
  for (int t = 0; t < T; ++t) {
    const int cb = t & 1;
    S_BARRIER();  // prior compute on buf cb^1 finished everywhere
    const int kn = (t + 1 < T) ? ((t + 1) << 6) : 0;  // wrap: harmless refetch
    if (cb == 0) GEMM_ISSUE(AsW1, BsW1, kn) else GEMM_ISSUE(AsW0, BsW0, kn);
    if constexpr (TM == 128)
      asm volatile("s_waitcnt vmcnt(6)" ::: "memory");  // tile-t loads landed
    else
      asm volatile("s_waitcnt vmcnt(4)" ::: "memory");
    S_BARRIER();
#pragma unroll
    for (int kk = 0; kk < 2; ++kk) {
      bf16x8 af[MT], bfr[2];
#pragma unroll
      for (int mt = 0; mt < MT; ++mt)
        af[mt] = *(const bf16x8*)&As[cb][(wm + mt * 16 + l16) * 64 +
                                        ((kk * 4 + quad) ^ swz) * 8];
#pragma unroll
      for (int nt = 0; nt < 2; ++nt)
        bfr[nt] = *(const bf16x8*)&Bs[cb][(wn + nt * 16 + l16) * 64 +
                                          ((kk * 4 + quad) ^ swz) * 8];
#pragma unroll
      for (int mt = 0; mt < MT; ++mt)
#pragma unroll
        for (int nt = 0; nt < 2; ++nt)
          acc[mt][nt] = mfma16(af[mt], bfr[nt], acc[mt][nt]);
    }
  }
  asm volatile("s_waitcnt vmcnt(0)" ::: "memory");  // drain before LDS dealloc

#pragma unroll
  for (int nt = 0; nt < 2; ++nt) {
    int col = n0 + wn + nt * 16 + l16;
    float bv = bias[col];
#pragma unroll
    for (int mt = 0; mt < MT; ++mt) {
#pragma unroll
      for (int r = 0; r < 4; ++r) {
        int row = m0 + wm + mt * 16 + quad * 4 + r;  // D: row=quad*4+r, col=l16
        float v = acc[mt][nt][r] + bv;
        if (res) v += bf2f(res[(size_t)row * N + col]);
        if (relu) v = fmaxf(v, 0.f);
        if (f32out)
          ((float*)Cout)[(size_t)row * N + col] = v;
        else
          ((u16*)Cout)[(size_t)row * N + col] = f2bf(v);
      }
    }
  }
}

// ---------------------------------------------------------------------------
// Flash attention, transposed: S^T = K@Q^T, ctx^T = V^T@P^T. Fixed-base
// softmax (Q pre-scaled 1/8); l via ones-MFMA on the bf16 P (self-consistent
// with truncation pack). Block = 128 q-rows x (b,h); wave = 32 q-rows.
// 1D grid 512, XCD-swizzled: bh = i&31 -> 4 heads' K/V (2MB) per XCD L2.
// ---------------------------------------------------------------------------
__global__ __launch_bounds__(256, 2) void attn_kernel(
    const u16* __restrict__ QKV, const u16* __restrict__ Vt,
    u16* __restrict__ O) {
  __shared__ alignas(16) u16 Ks[2][64 * 64];  // [key][d], swizzled
  __shared__ alignas(16) u16 Vs[2][64 * 64];  // [d][s], swizzled
  __shared__ alignas(16) u16 Ps[4][32 * 72];  // per-wave P[qrow][key]
  const int tid = threadIdx.x;
  const int wave = tid >> 6, lane = tid & 63;
  const int quad = lane >> 4, l16 = lane & 15;
  const int ib = blockIdx.x;
  const int bh = ib & 31, b = bh >> 4, h = bh & 15;
  const int q0 = (ib >> 5) * 128 + wave * 32;

  // Q as B-frags (k=d=quad*8+j, n=qrow=l16), pre-scaled by 1/8 (exact)
  bf16x8 qf[2][2];
#pragma unroll
  for (int qt = 0; qt < 2; ++qt) {
    const size_t qoff = (size_t)(b * 2048 + q0 + qt * 16 + l16) * 3072 + h * 64;
#pragma unroll
    for (int kk = 0; kk < 2; ++kk) {
      bf16x8 raw = *(const bf16x8*)&QKV[qoff + kk * 32 + quad * 8];
#pragma unroll
      for (int u = 0; u < 8; ++u)
        ((u16*)&raw)[u] = f2bf(0.125f * bf2f(((u16*)&raw)[u]));
      qf[qt][kk] = raw;
    }
  }
  bf16x8 ones;
#pragma unroll
  for (int u = 0; u < 8; ++u) ((u16*)&ones)[u] = 0x3F80;  // 1.0bf

  f32x4 o[4][2];  // ctx^T [d-tile][q-tile]
  f32x4 l_acc[2] = {(f32x4){0.f, 0.f, 0.f, 0.f}, (f32x4){0.f, 0.f, 0.f, 0.f}};
#pragma unroll
  for (int mt = 0; mt < 4; ++mt)
#pragma unroll
    for (int qt = 0; qt < 2; ++qt) o[mt][qt] = (f32x4){0.f, 0.f, 0.f, 0.f};

  const int srow = lane >> 3;
  const int schunk = (lane & 7) ^ (srow & 7);
  const u16* Kg = QKV + (size_t)(b * 2048 + wave * 16 + srow) * 3072 + 1024 +
                  h * 64 + schunk * 8;
  const u16* Vg = Vt + (size_t)((b * 16 + h) * 64 + wave * 16 + srow) * 2048 +
                  schunk * 8;
  u16* KsW0 = &Ks[0][(wave * 16) * 64];
  u16* VsW0 = &Vs[0][(wave * 16) * 64];
  u16* KsW1 = &Ks[1][(wave * 16) * 64];
  u16* VsW1 = &Vs[1][(wave * 16) * 64];

#define ATTN_ISSUE(kb, vb, kt)                                \
  {                                                           \
    async_cp16(Kg + (size_t)(kt) * 3072, (kb));               \
    async_cp16(Kg + (size_t)((kt) + 8) * 3072, (kb) + 512);   \
    async_cp16(Vg + (kt), (vb));                              \
    async_cp16(Vg + (kt) + (size_t)8 * 2048, (vb) + 512);     \
  }

  ATTN_ISSUE(KsW0, VsW0, 0);
  const int swz = (l16 & 7);
  u16* PsW = &Ps[wave][0];
  for (int t = 0; t < 32; ++t) {
    const int cb = t & 1;
    S_BARRIER();
    const int ktn = (t + 1 < 32) ? ((t + 1) * 64) : 0;
    if (cb == 0) ATTN_ISSUE(KsW1, VsW1, ktn) else ATTN_ISSUE(KsW0, VsW0, ktn);
    asm volatile("s_waitcnt vmcnt(4)" ::: "memory");
    S_BARRIER();

    // S^T = K @ Q^T : D[m=key][n=qrow]
    f32x4 st[4][2];
#pragma unroll
    for (int km = 0; km < 4; ++km)
#pragma unroll
      for (int qt = 0; qt < 2; ++qt) st[km][qt] = (f32x4){0.f, 0.f, 0.f, 0.f};
#pragma unroll
    for (int kk = 0; kk < 2; ++kk)
#pragma unroll
      for (int km = 0; km < 4; ++km) {
        bf16x8 kf = *(const bf16x8*)&Ks[cb][(km * 16 + l16) * 64 +
                                           ((kk * 4 + quad) ^ swz) * 8];
        st[km][0] = mfma16(kf, qf[0][kk], st[km][0]);
        st[km][1] = mfma16(kf, qf[1][kk], st[km][1]);
      }

    // exp + truncating v_perm pack -> one b64 write per (qt,km)
#pragma unroll
    for (int qt = 0; qt < 2; ++qt)
#pragma unroll
      for (int km = 0; km < 4; ++km) {
        float e0 = __expf(st[km][qt][0]), e1 = __expf(st[km][qt][1]);
        float e2 = __expf(st[km][qt][2]), e3 = __expf(st[km][qt][3]);
        uint2 pk;
        pk.x = pk2t(e0, e1);
        pk.y = pk2t(e2, e3);
        *(uint2*)&PsW[(qt * 16 + l16) * 72 + km * 16 + quad * 4] = pk;
      }
    asm volatile("s_waitcnt lgkmcnt(0)" ::: "memory");  // wave-local round-trip

    // ctx^T += V^T @ P^T ; l += ones @ P^T (row sums of bf16 P)
#pragma unroll
    for (int kk2 = 0; kk2 < 2; ++kk2) {
      bf16x8 pf0 = *(const bf16x8*)&PsW[l16 * 72 + kk2 * 32 + quad * 8];
      bf16x8 pf1 = *(const bf16x8*)&PsW[(16 + l16) * 72 + kk2 * 32 + quad * 8];
      l_acc[0] = mfma16(ones, pf0, l_acc[0]);
      l_acc[1] = mfma16(ones, pf1, l_acc[1]);
#pragma unroll
      for (int mt = 0; mt < 4; ++mt) {
        bf16x8 vf = *(const bf16x8*)&Vs[cb][(mt * 16 + l16) * 64 +
                                           ((kk2 * 4 + quad) ^ swz) * 8];
        o[mt][0] = mfma16(vf, pf0, o[mt][0]);
        o[mt][1] = mfma16(vf, pf1, o[mt][1]);
      }
    }
  }
  asm volatile("s_waitcnt vmcnt(0)" ::: "memory");  // drain before LDS dealloc

  // epilogue: lane holds ctx^T[d=mt*16+quad*4+r][qrow=qt*16+l16]; l_acc rows
  // are all identical (= sum over keys for qrow=l16) -> no shuffles needed
#pragma unroll
  for (int qt = 0; qt < 2; ++qt) {
    float inv = 1.f / l_acc[qt][0];
    size_t base = (size_t)(b * 2048 + q0 + qt * 16 + l16) * 1024 + h * 64;
#pragma unroll
    for (int mt = 0; mt < 4; ++mt) {
      uint2 pk;
      pk.x = pk2(o[mt][qt][0] * inv, o[mt][qt][1] * inv);
      pk.y = pk2(o[mt][qt][2] * inv, o[mt][qt][3] * inv);
      *(uint2*)&O[base + mt * 16 + quad * 4] = pk;
    }
  }
}

// v slice of qkv [B,S,3072] -> vt [B,H,64,S]; grid (S/64, B*H)
__global__ __launch_bounds__(256) void transpose_v(const u16* __restrict__ QKV,
                                                   u16* __restrict__ vt) {
  const int bh = blockIdx.y;
  const int b = bh >> 4, h = bh & 15;
  const int s0 = blockIdx.x * 64;
  const u16* in = QKV + (size_t)b * 2048 * 3072 + 2048 + h * 64;
  u16* out = vt + (size_t)bh * 131072;
  __shared__ alignas(16) u16 T[64][TSP];
  const int tid = threadIdx.x;
#pragma unroll
  for (int it = 0; it < 2; ++it) {
    int vi = it * 256 + tid;
    int i = vi >> 3, j8 = (vi & 7) * 8;
    *(bf16x8*)&T[i][j8] = *(const bf16x8*)&in[(size_t)(s0 + i) * 3072 + j8];
  }
  __syncthreads();
#pragma unroll
  for (int it = 0; it < 2; ++it) {
    int vi = it * 256 + tid;
    int i = vi >> 3, j8 = (vi & 7) * 8;  // i = d, j8 over s
    bf16x8 vv;
#pragma unroll
    for (int u = 0; u < 8; ++u) ((u16*)&vv)[u] = T[j8 + u][i];
    *(bf16x8*)&out[(size_t)i * 2048 + s0 + j8] = vv;
  }
}

// ---------------------------------------------------------------------------
extern "C" void kernel_launch(void* const* d_in, const int* in_sizes, int n_in,
                              void* d_out, int out_size, void* d_ws,
                              size_t ws_size, hipStream_t stream) {
  const float* x = (const float*)d_in[0];
  const float* We = (const float*)d_in[1];
  const float* be = (const float*)d_in[2];
  const float* Wq = (const float*)d_in[3];
  const float* bq = (const float*)d_in[4];
  const float* Wk = (const float*)d_in[5];
  const float* bk = (const float*)d_in[6];
  const float* Wv = (const float*)d_in[7];
  const float* bv = (const float*)d_in[8];
  const float* W0 = (const float*)d_in[9];
  const float* b0 = (const float*)d_in[10];
  const float* W1 = (const float*)d_in[11];
  const float* b1 = (const float*)d_in[12];
  const float* W2 = (const float*)d_in[13];
  const float* b2 = (const float*)d_in[14];

  u16* ws = (u16*)d_ws;
  u16* xb = ws;                         // 2,097,152
  u16* Wet = xb + 2097152;              //   524,288
  u16* qkvWt = Wet + 524288;            // 3,145,728
  u16* ctx = ws;                        // alias after qkv-gemm
  u16* W0t = qkvWt + 3145728;
  u16* W1t = W0t + 1048576;
  u16* W2t = W1t + 1048576;
  float* biasqkv = (float*)(W2t + 1048576);  // 3072 f32
  u16* e = W2t + 1048576 + 6144;
  u16* qkv = e + 4194304;               // 12,582,912
  u16* vtb = qkv + 12582912;
  u16* mha = qkv;                       // alias: qkv dead after attn
  u16* h1 = e;                          // alias: e dead after W0-gemm

  cast_f32_bf16<<<2048, 256, 0, stream>>>(x, xb, 4096 * 512);
  transpose_weights<<<dim3(16, 16, 7), 256, 0, stream>>>(
      We, Wq, Wk, Wv, W0, W1, W2, Wet, qkvWt, W0t, W1t, W2t);
  biascat<<<12, 256, 0, stream>>>(bq, bk, bv, biasqkv);

  // e = x @ We + be
  gemm_mfma<64><<<1024, 256, 0, stream>>>(xb, Wet, be, nullptr, e, 4096, 1024,
                                          512, 0, 0);
  // qkv = e @ [Wq|Wk|Wv] + [bq|bk|bv]
  gemm_mfma<128><<<1536, 256, 0, stream>>>(e, qkvWt, biasqkv, nullptr, qkv,
                                           4096, 3072, 1024, 0, 0);
  transpose_v<<<dim3(32, 32), 256, 0, stream>>>(qkv, vtb);
  attn_kernel<<<512, 256, 0, stream>>>(qkv, vtb, ctx);
  // mha = e + ctx @ W0 + b0
  gemm_mfma<64><<<1024, 256, 0, stream>>>(ctx, W0t, b0, e, mha, 4096, 1024,
                                          1024, 0, 0);
  // h1 = relu(mha @ W1 + b1)
  gemm_mfma<64><<<1024, 256, 0, stream>>>(mha, W1t, b1, nullptr, h1, 4096,
                                          1024, 1024, 1, 0);
  // out = mha + h1 @ W2 + b2 (f32)
  gemm_mfma<64><<<1024, 256, 0, stream>>>(h1, W2t, b2, mha, d_out, 4096, 1024,
                                          1024, 0, 1);
}